// Round 6
// baseline (307.524 us; speedup 1.0000x reference)
//
#include <hip/hip_runtime.h>

// Problem constants
#define B_  2
#define S_  1024
#define FIN 768
#define E_  768
#define H_  12
#define DH  64   // = FH = 64

typedef unsigned int uint;

__device__ __forceinline__ float bcast_lane(float v, int l) {
    return __uint_as_float((uint)__builtin_amdgcn_readlane((int)__float_as_uint(v), l));
}

__device__ __forceinline__ void wsum64x2(float& a, float& b) {
#pragma unroll
    for (int m = 1; m < 64; m <<= 1) {
        a += __shfl_xor(a, m, 64);
        b += __shfl_xor(b, m, 64);
    }
}

// ---------------------------------------------------------------------------
// K1: block 0: normalize nnmf_w rows -> Wn, WnT. Blocks 1..24: zero mp0.
// Block 1 also zeros the grid-barrier counter.
// ---------------------------------------------------------------------------
__global__ __launch_bounds__(256) void k_wprep(const float* __restrict__ nw,
                                               float* __restrict__ Wn,
                                               float* __restrict__ WnT,
                                               float* __restrict__ mp0,
                                               uint* __restrict__ bar) {
    const int tid = threadIdx.x;
    if (blockIdx.x == 0) {
        const int f = tid >> 2, q = tid & 3;
        float v[16];
        float s = 0.f;
#pragma unroll
        for (int i = 0; i < 16; ++i) { v[i] = nw[f * 64 + q * 16 + i]; s += v[i]; }
        s += __shfl_xor(s, 1, 64);
        s += __shfl_xor(s, 2, 64);
        const float inv = 1.f / fmaxf(s, 1e-20f);
#pragma unroll
        for (int i = 0; i < 16; ++i) {
            float w = v[i] * inv;
            Wn[f * 64 + q * 16 + i] = w;
            WnT[(q * 16 + i) * 64 + f] = w;
        }
    } else {
        const int blk = blockIdx.x - 1;   // 0..23
        float4 z = make_float4(0.f, 0.f, 0.f, 0.f);
        *(float4*)(mp0 + (size_t)blk * 1024 + tid * 4) = z;
        if (blk == 0 && tid < 8) bar[tid] = 0u;
    }
}

// ---------------------------------------------------------------------------
// K2 (= R4 best): xe = clip(x @ embed_w^T + b, 1e-6); inp = l1norm per head.
// 32 tok x 64 out tiles -> 768 blocks. Thread-tile 2x4, k-major LDS 26 KB.
// ---------------------------------------------------------------------------
__global__ __launch_bounds__(256) void k_embed(const float* __restrict__ xs,
                                               const float* __restrict__ ew,
                                               const float* __restrict__ eb,
                                               float* __restrict__ inp) {
    __shared__ float As[64 * 34];
    __shared__ float Bs[64 * 68];
    const int tid = threadIdx.x;
    const int head = blockIdx.y;
    const int tok0 = blockIdx.x * 32;
    const int og = tid & 15;
    const int tg = tid >> 4;

    float acc[2][4];
#pragma unroll
    for (int i = 0; i < 2; ++i)
#pragma unroll
        for (int j = 0; j < 4; ++j) acc[i][j] = 0.f;

    const int arow = tid & 31, akc = (tid >> 5) * 8;
    const int brow = tid & 63, bkc = (tid >> 6) * 16;
    const float* xrow = xs + (size_t)(tok0 + arow) * FIN + akc;
    const float* wrow = ew + (size_t)(head * 64 + brow) * FIN + bkc;

    float4 pa0 = *(const float4*)(xrow);
    float4 pa1 = *(const float4*)(xrow + 4);
    float4 pb[4];
#pragma unroll
    for (int c = 0; c < 4; ++c) pb[c] = *(const float4*)(wrow + c * 4);

    for (int kb = 0; kb < FIN; kb += 64) {
        __syncthreads();
        As[(akc + 0) * 34 + arow] = pa0.x; As[(akc + 1) * 34 + arow] = pa0.y;
        As[(akc + 2) * 34 + arow] = pa0.z; As[(akc + 3) * 34 + arow] = pa0.w;
        As[(akc + 4) * 34 + arow] = pa1.x; As[(akc + 5) * 34 + arow] = pa1.y;
        As[(akc + 6) * 34 + arow] = pa1.z; As[(akc + 7) * 34 + arow] = pa1.w;
#pragma unroll
        for (int c = 0; c < 4; ++c) {
            int k = bkc + c * 4;
            Bs[(k + 0) * 68 + brow] = pb[c].x; Bs[(k + 1) * 68 + brow] = pb[c].y;
            Bs[(k + 2) * 68 + brow] = pb[c].z; Bs[(k + 3) * 68 + brow] = pb[c].w;
        }
        __syncthreads();
        if (kb + 64 < FIN) {
            pa0 = *(const float4*)(xrow + kb + 64);
            pa1 = *(const float4*)(xrow + kb + 68);
#pragma unroll
            for (int c = 0; c < 4; ++c) pb[c] = *(const float4*)(wrow + kb + 64 + c * 4);
        }
#pragma unroll 8
        for (int k = 0; k < 64; ++k) {
            float2 a2 = *(const float2*)&As[k * 34 + tg * 2];
            float4 b4 = *(const float4*)&Bs[k * 68 + og * 4];
            acc[0][0] = fmaf(a2.x, b4.x, acc[0][0]);
            acc[0][1] = fmaf(a2.x, b4.y, acc[0][1]);
            acc[0][2] = fmaf(a2.x, b4.z, acc[0][2]);
            acc[0][3] = fmaf(a2.x, b4.w, acc[0][3]);
            acc[1][0] = fmaf(a2.y, b4.x, acc[1][0]);
            acc[1][1] = fmaf(a2.y, b4.y, acc[1][1]);
            acc[1][2] = fmaf(a2.y, b4.z, acc[1][2]);
            acc[1][3] = fmaf(a2.y, b4.w, acc[1][3]);
        }
    }

    float4 bias = *(const float4*)(eb + head * 64 + og * 4);
    float bb[4] = {bias.x, bias.y, bias.z, bias.w};
#pragma unroll
    for (int i = 0; i < 2; ++i) {
        float p = 0.f;
#pragma unroll
        for (int j = 0; j < 4; ++j) {
            float xe = fmaxf(acc[i][j] + bb[j], 1e-6f);
            acc[i][j] = xe;
            p += xe;
        }
        p += __shfl_xor(p, 1, 64);
        p += __shfl_xor(p, 2, 64);
        p += __shfl_xor(p, 4, 64);
        p += __shfl_xor(p, 8, 64);
        const float inv = 1.f / fmaxf(p, 1e-20f);
        const int g = tok0 + tg * 2 + i;
        const int b = g >> 10, s = g & 1023;
        float4 o;
        o.x = acc[i][0] * inv; o.y = acc[i][1] * inv;
        o.z = acc[i][2] * inv; o.w = acc[i][3] * inv;
        *(float4*)(inp + ((size_t)((b * 12 + head) * 1024 + s)) * 64 + og * 4) = o;
    }
}

// ---------------------------------------------------------------------------
// K3: NNMF updates, 1536 blocks, wave = 4 token-heads processed as 2 ILP pairs.
// Fuses it=0 alpha partial via atomicAdd into mp0.
// ---------------------------------------------------------------------------
__global__ __launch_bounds__(256) void k_nnmf(const float* __restrict__ inp,
                                              const float* __restrict__ Wn,
                                              const float* __restrict__ WnT,
                                              float* __restrict__ hout,
                                              float* __restrict__ hriout,
                                              float* __restrict__ mp0) {
    const int tid = threadIdx.x;
    const int lane = tid & 63;
    float wcol[64], wrw[64];
#pragma unroll
    for (int f = 0; f < 64; ++f) wcol[f] = Wn[f * 64 + lane];   // W[f][lane]
#pragma unroll
    for (int d = 0; d < 64; ++d) wrw[d] = WnT[d * 64 + lane];   // W[lane][d]

    const int wid = blockIdx.x * 4 + (tid >> 6);
    float hsum = 0.f;
    for (int tt = 0; tt < 2; ++tt) {
        const int th0 = wid * 4 + tt * 2;
        const size_t base = (size_t)th0 * 64;
        float iv[2] = {inp[base + lane], inp[base + 64 + lane]};
        float hv[2] = {1.f / 64.f, 1.f / 64.f};
        float rec[2] = {0.f, 0.f};
        for (int it = 0; it < 3; ++it) {
            float ta[2] = {0.f, 0.f}, tb[2] = {0.f, 0.f};
#pragma unroll
            for (int f = 0; f < 64; f += 2) {
#pragma unroll
                for (int p = 0; p < 2; ++p) {
                    ta[p] = fmaf(bcast_lane(hv[p], f    ), wcol[f    ], ta[p]);
                    tb[p] = fmaf(bcast_lane(hv[p], f + 1), wcol[f + 1], tb[p]);
                }
            }
            float t[2], w[2];
            t[0] = fmaxf(ta[0] + tb[0], 1e-6f);
            t[1] = fmaxf(ta[1] + tb[1], 1e-6f);
            w[0] = t[0]; w[1] = t[1];
            wsum64x2(w[0], w[1]);
            rec[0] = t[0] / fmaxf(w[0], 1e-20f);
            rec[1] = t[1] / fmaxf(w[1], 1e-20f);
            float q[2] = {iv[0] / rec[0], iv[1] / rec[1]};
            float ua[2] = {0.f, 0.f}, ub[2] = {0.f, 0.f};
#pragma unroll
            for (int d = 0; d < 64; d += 2) {
#pragma unroll
                for (int p = 0; p < 2; ++p) {
                    ua[p] = fmaf(bcast_lane(q[p], d    ), wrw[d    ], ua[p]);
                    ub[p] = fmaf(bcast_lane(q[p], d + 1), wrw[d + 1], ub[p]);
                }
            }
            float hn[2];
            hn[0] = fmaxf(hv[0] * (ua[0] + ub[0]), 1e-6f);
            hn[1] = fmaxf(hv[1] * (ua[1] + ub[1]), 1e-6f);
            float wn[2] = {hn[0], hn[1]};
            wsum64x2(wn[0], wn[1]);
            hv[0] = hn[0] / fmaxf(wn[0], 1e-20f);
            hv[1] = hn[1] / fmaxf(wn[1], 1e-20f);
        }
        float fs[2] = {hv[0], hv[1]};
        wsum64x2(fs[0], fs[1]);
        hv[0] = hv[0] / fmaxf(fs[0], 1e-20f);
        hv[1] = hv[1] / fmaxf(fs[1], 1e-20f);
        hout[base + lane] = hv[0];
        hout[base + 64 + lane] = hv[1];
        hriout[base + lane] = rec[0] * iv[0];
        hriout[base + 64 + lane] = rec[1] * iv[1];
        hsum += hv[0] + hv[1];
    }
    atomicAdd(&mp0[(size_t)(wid >> 4) * 64 + lane], hsum);
}

// ---------------------------------------------------------------------------
// K4: PERSISTENT alpha (3 iterations) + out-projection + broadcast.
// 384 blocks (all co-resident: 256 thr, ~6 KB LDS, modest VGPR). Manual
// device-scope grid barrier. h/hri chunks live in registers; c in LDS.
// ---------------------------------------------------------------------------
__device__ __forceinline__ void gridbar(uint* bar, uint expect) {
    __syncthreads();
    if (threadIdx.x == 0) {
        __threadfence();
        __hip_atomic_fetch_add(bar, 1u, __ATOMIC_ACQ_REL, __HIP_MEMORY_SCOPE_AGENT);
        while (__hip_atomic_load(bar, __ATOMIC_ACQUIRE, __HIP_MEMORY_SCOPE_AGENT) < expect) {
            __builtin_amdgcn_s_sleep(2);
        }
        __threadfence();
    }
    __syncthreads();
}

__global__ __launch_bounds__(256, 2) void k_alpha_proj(const float* __restrict__ hin,
                                                       const float* __restrict__ hri,
                                                       const float* __restrict__ Wn,
                                                       const float* __restrict__ mp0,
                                                       float* __restrict__ mpA,
                                                       float* __restrict__ mpB,
                                                       float* __restrict__ mpM,
                                                       const float* __restrict__ ow,
                                                       const float* __restrict__ ob,
                                                       float* __restrict__ out,
                                                       uint* __restrict__ bar) {
    __shared__ float mred[4][64];
    __shared__ float mv[64];
    __shared__ float vv[64];
    __shared__ float cl[64];
    __shared__ float Ml[768];
    __shared__ float ps[4][64];
    __shared__ float yseg[64];
    const int tid = threadIdx.x;
    const int bh = blockIdx.x >> 4;
    const int chunk = blockIdx.x & 15;
    const size_t rowbase = (size_t)bh * 1024 + chunk * 64;

    // preload this block's h and hri chunks into registers (two layouts)
    const int o_h = tid >> 2, dq = tid & 3;          // hri layout
    const int f4 = (tid & 15) * 4, og = tid >> 4;    // h layout
    float4 hr4[4];   // hri[o_h][dq*16 .. +15]
#pragma unroll
    for (int q = 0; q < 4; ++q)
        hr4[q] = *(const float4*)(hri + (rowbase + o_h) * 64 + dq * 16 + q * 4);
    float4 hh4[4];   // h[og*4+oi][f4 .. +3]
#pragma unroll
    for (int oi = 0; oi < 4; ++oi)
        hh4[oi] = *(const float4*)(hin + (rowbase + og * 4 + oi) * 64 + f4);

    const float* mp_in = mp0;
    for (int it = 1; it <= 3; ++it) {
        // m[f] = sum over 16 chunks of mp_in[bh][ch][f]
        {
            int f = tid & 63, p = tid >> 6;
            float s = 0.f;
#pragma unroll
            for (int pp = 0; pp < 4; ++pp)
                s += mp_in[((size_t)bh * 16 + p * 4 + pp) * 64 + f];
            mred[p][f] = s;
        }
        __syncthreads();
        if (tid < 64)
            mv[tid] = (mred[0][tid] + mred[1][tid]) + (mred[2][tid] + mred[3][tid]);
        __syncthreads();
        // v[d] = 1/(sum_f m[f]*W[f][d] + eps)
        {
            int d = tid & 63, qq = tid >> 6;
            float r = 0.f;
#pragma unroll
            for (int ff = 0; ff < 16; ++ff)
                r = fmaf(mv[qq * 16 + ff], Wn[(size_t)(qq * 16 + ff) * 64 + d], r);
            mred[qq][d] = r;
        }
        __syncthreads();
        if (tid < 64)
            vv[tid] = 1.f / (((mred[0][tid] + mred[1][tid]) + (mred[2][tid] + mred[3][tid])) + 1e-20f);
        __syncthreads();
        // c-update from registers: c[o] *= dot(hri[o,:], v)
        {
            float dot = 0.f;
#pragma unroll
            for (int q = 0; q < 4; ++q) {
                dot = fmaf(hr4[q].x, vv[dq * 16 + q * 4 + 0], dot);
                dot = fmaf(hr4[q].y, vv[dq * 16 + q * 4 + 1], dot);
                dot = fmaf(hr4[q].z, vv[dq * 16 + q * 4 + 2], dot);
                dot = fmaf(hr4[q].w, vv[dq * 16 + q * 4 + 3], dot);
            }
            dot += __shfl_xor(dot, 1, 64);
            dot += __shfl_xor(dot, 2, 64);
            if (dq == 0) {
                float cn = dot;
                if (it >= 2) cn *= cl[o_h];
                cl[o_h] = cn;
            }
        }
        __syncthreads();
        // partial m for this chunk from h registers
        {
            float4 a = make_float4(0.f, 0.f, 0.f, 0.f);
#pragma unroll
            for (int oi = 0; oi < 4; ++oi) {
                float cv = cl[og * 4 + oi];
                a.x = fmaf(hh4[oi].x, cv, a.x); a.y = fmaf(hh4[oi].y, cv, a.y);
                a.z = fmaf(hh4[oi].z, cv, a.z); a.w = fmaf(hh4[oi].w, cv, a.w);
            }
            a.x += __shfl_xor(a.x, 16, 64); a.y += __shfl_xor(a.y, 16, 64);
            a.z += __shfl_xor(a.z, 16, 64); a.w += __shfl_xor(a.w, 16, 64);
            a.x += __shfl_xor(a.x, 32, 64); a.y += __shfl_xor(a.y, 32, 64);
            a.z += __shfl_xor(a.z, 32, 64); a.w += __shfl_xor(a.w, 32, 64);
            const int w = tid >> 6;
            if ((tid & 63) < 16) *(float4*)&mred[w][(tid & 15) * 4] = a;
        }
        __syncthreads();
        float* mp_out = (it == 1) ? mpA : (it == 2) ? mpB : mpM;
        if (tid < 64)
            mp_out[((size_t)bh * 16 + chunk) * 64 + tid] =
                (mred[0][tid] + mred[1][tid]) + (mred[2][tid] + mred[3][tid]);
        gridbar(bar, 384u * (uint)it);
        mp_in = mp_out;
    }

    // ---- projection + broadcast phase: block = (b, jt, rowgroup) ----
    const int b = blockIdx.x / 192;
    const int rem = blockIdx.x - b * 192;
    const int jt = rem >> 4, rg = rem & 15;
    for (int i = tid; i < 768; i += 256) {
        int hh = i >> 6, f = i & 63;
        const float* mp = mpM + ((size_t)(b * 12 + hh) * 16) * 64 + f;
        float s = 0.f;
#pragma unroll
        for (int ch = 0; ch < 16; ++ch) s += mp[ch * 64];
        Ml[i] = s;
    }
    __syncthreads();
    const int jj = tid & 63, part = tid >> 6;
    const int j = jt * 64 + jj;
    const float* row = ow + (size_t)j * 768 + part * 192;
    float acc = 0.f;
    for (int t = 0; t < 192; t += 4) {
        float4 w4 = *(const float4*)(row + t);
        acc = fmaf(w4.x, Ml[part * 192 + t + 0], acc);
        acc = fmaf(w4.y, Ml[part * 192 + t + 1], acc);
        acc = fmaf(w4.z, Ml[part * 192 + t + 2], acc);
        acc = fmaf(w4.w, Ml[part * 192 + t + 3], acc);
    }
    ps[part][jj] = acc;
    __syncthreads();
    if (tid < 64)
        yseg[tid] = ps[0][tid] + ps[1][tid] + ps[2][tid] + ps[3][tid] + ob[jt * 64 + tid];
    __syncthreads();
    const int r0 = tid >> 2, c4 = (tid & 3) * 16;
    float4 v4[4];
#pragma unroll
    for (int q = 0; q < 4; ++q) v4[q] = *(const float4*)&yseg[c4 + q * 4];
    float* dst = out + ((size_t)(b * 1024 + rg * 64 + r0)) * 768 + jt * 64 + c4;
#pragma unroll
    for (int q = 0; q < 4; ++q) *(float4*)(dst + q * 4) = v4[q];
}

extern "C" void kernel_launch(void* const* d_in, const int* in_sizes, int n_in,
                              void* d_out, int out_size, void* d_ws, size_t ws_size,
                              hipStream_t stream) {
    const float* xs = (const float*)d_in[0];  // [2,1024,768]
    const float* ew = (const float*)d_in[1];  // [768,768]
    const float* eb = (const float*)d_in[2];  // [768]
    const float* nw = (const float*)d_in[3];  // [64,64]
    const float* ow = (const float*)d_in[4];  // [768,768]
    const float* ob = (const float*)d_in[5];  // [768]
    float* out = (float*)d_out;               // [2,1024,768]

    float* ws  = (float*)d_ws;
    float* inp = ws;                 // 1572864
    float* h   = ws + 1572864;       // 1572864
    float* hri = ws + 3145728;       // 1572864
    float* Wn  = ws + 4718592;       // 4096
    float* WnT = ws + 4722688;       // 4096
    float* mp0 = ws + 4726784;       // 24576 (atomic target, zeroed by k_wprep)
    float* mpA = ws + 4751360;       // 24576
    float* mpB = ws + 4775936;       // 24576
    float* mpM = ws + 4800512;       // 24576
    uint*  bar = (uint*)(ws + 4825088);

    k_wprep<<<25, 256, 0, stream>>>(nw, Wn, WnT, mp0, bar);
    k_embed<<<dim3(64, 12), 256, 0, stream>>>(xs, ew, eb, inp);
    k_nnmf<<<1536, 256, 0, stream>>>(inp, Wn, WnT, h, hri, mp0);
    k_alpha_proj<<<384, 256, 0, stream>>>(h, hri, Wn, mp0, mpA, mpB, mpM,
                                          ow, ob, out, bar);
}

// Round 7
// 157.519 us; speedup vs baseline: 1.9523x; 1.9523x over previous
//
#include <hip/hip_runtime.h>

// Problem constants
#define B_  2
#define S_  1024
#define FIN 768
#define E_  768
#define H_  12
#define DH  64   // = FH = 64

typedef unsigned int uint;
typedef unsigned short ushort;
typedef __attribute__((ext_vector_type(8))) short short8;    // 8 bf16 (4 VGPRs)
typedef __attribute__((ext_vector_type(4))) float floatx4;   // MFMA acc

__device__ __forceinline__ float bcast_lane(float v, int l) {
    return __uint_as_float((uint)__builtin_amdgcn_readlane((int)__float_as_uint(v), l));
}

__device__ __forceinline__ void wsum64x2(float& a, float& b) {
#pragma unroll
    for (int m = 1; m < 64; m <<= 1) {
        a += __shfl_xor(a, m, 64);
        b += __shfl_xor(b, m, 64);
    }
}

__device__ __forceinline__ ushort f2bf(float f) {   // RNE float->bf16 bits
    uint u = __float_as_uint(f);
    return (ushort)((u + 0x7fffu + ((u >> 16) & 1u)) >> 16);
}

__device__ __forceinline__ uint4 pack8(const ushort* p) {
    uint4 r;
    r.x = (uint)p[0] | ((uint)p[1] << 16);
    r.y = (uint)p[2] | ((uint)p[3] << 16);
    r.z = (uint)p[4] | ((uint)p[5] << 16);
    r.w = (uint)p[6] | ((uint)p[7] << 16);
    return r;
}

// ---------------------------------------------------------------------------
// K1: block 0: Wn/WnT (row-normalized nnmf_w) + r1inv (iteration-1 collapsed
// reconstruction: rec1[d] = l1norm(clip(colmean(Wn)))[d], store 1/rec1).
// Blocks 1..26: zero mp0 (24576) + M (1536) — contiguous 26112 floats.
// ---------------------------------------------------------------------------
__global__ __launch_bounds__(256) void k_wprep(const float* __restrict__ nw,
                                               float* __restrict__ Wn,
                                               float* __restrict__ WnT,
                                               float* __restrict__ r1inv,
                                               float* __restrict__ zbase) {
    const int tid = threadIdx.x;
    if (blockIdx.x == 0) {
        __shared__ float Wl[64 * 65];
        const int f = tid >> 2, q = tid & 3;
        float v[16];
        float s = 0.f;
#pragma unroll
        for (int i = 0; i < 16; ++i) { v[i] = nw[f * 64 + q * 16 + i]; s += v[i]; }
        s += __shfl_xor(s, 1, 64);
        s += __shfl_xor(s, 2, 64);
        const float inv = 1.f / fmaxf(s, 1e-20f);
#pragma unroll
        for (int i = 0; i < 16; ++i) {
            float w = v[i] * inv;
            Wn[f * 64 + q * 16 + i] = w;
            WnT[(q * 16 + i) * 64 + f] = w;
            Wl[f * 65 + q * 16 + i] = w;
        }
        __syncthreads();
        if (tid < 64) {
            float cs = 0.f;
            for (int ff = 0; ff < 64; ++ff) cs += Wl[ff * 65 + tid];
            float t = fmaxf(cs * (1.f / 64.f), 1e-6f);
            float S = t;
#pragma unroll
            for (int m = 1; m < 64; m <<= 1) S += __shfl_xor(S, m, 64);
            S = fmaxf(S, 1e-20f);
            // rec1[d] = t/S ; r1inv = S/t
            r1inv[tid] = S / t;
        }
    } else {
        const int i = (blockIdx.x - 1) * 1024 + tid * 4;
        if (i < 26112) {
            float4 z = make_float4(0.f, 0.f, 0.f, 0.f);
            *(float4*)(zbase + i) = z;
        }
    }
}

// ---------------------------------------------------------------------------
// K2 v5 (MFMA): xe = clip(x @ embed_w^T + b, 1e-6); inp = l1norm per head.
// Block: 64 tok x 64 out (one head), 384 blocks. Split-bf16 (hi+lo) inputs,
// 3 MFMA products per tile pair (hi*hi + lo*hi + hi*lo) -> fp32-grade result.
// 4 waves x (32x32 wave tile = 2x2 of 16x16x32 MFMA). K-panels of 64.
// LDS: 4 planes [64][72] bf16 = 36 KB (stride 72 -> 2-way conflicts = free).
// ---------------------------------------------------------------------------
__global__ __launch_bounds__(256) void k_embed(const float* __restrict__ xs,
                                               const float* __restrict__ ew,
                                               const float* __restrict__ eb,
                                               float* __restrict__ inp) {
    __shared__ ushort As_hi[64 * 72], As_lo[64 * 72];
    __shared__ ushort Bs_hi[64 * 72], Bs_lo[64 * 72];
    __shared__ float RS[2][64];
    const int tid = threadIdx.x;
    const int head = blockIdx.y;
    const int tok0 = blockIdx.x * 64;
    const int wv = tid >> 6, lane = tid & 63;
    const int mbase = (wv >> 1) * 32, nbase = (wv & 1) * 32;
    const int lm = lane & 15, lq = lane >> 4;

    floatx4 acc[2][2];
#pragma unroll
    for (int si = 0; si < 2; ++si)
#pragma unroll
        for (int ti = 0; ti < 2; ++ti) acc[si][ti] = (floatx4)0.f;

    const int row = tid >> 2;            // 0..63 (tok for A, out for B)
    const int kq = (tid & 3) * 16;       // 16 k per thread
    const float* xrow = xs + (size_t)(tok0 + row) * FIN + kq;
    const float* wrow = ew + (size_t)(head * 64 + row) * FIN + kq;

    float4 pa[4], pb[4];
#pragma unroll
    for (int c = 0; c < 4; ++c) {
        pa[c] = *(const float4*)(xrow + c * 4);
        pb[c] = *(const float4*)(wrow + c * 4);
    }

    for (int kb = 0; kb < FIN; kb += 64) {
        __syncthreads();   // previous panel's frag reads done
        {   // convert + stage A and B (hi/lo planes)
            ushort ah[16], al[16], bh[16], bl[16];
#pragma unroll
            for (int c4 = 0; c4 < 4; ++c4) {
                float va[4] = {pa[c4].x, pa[c4].y, pa[c4].z, pa[c4].w};
                float vb[4] = {pb[c4].x, pb[c4].y, pb[c4].z, pb[c4].w};
#pragma unroll
                for (int j = 0; j < 4; ++j) {
                    ushort h = f2bf(va[j]);
                    ah[c4 * 4 + j] = h;
                    al[c4 * 4 + j] = f2bf(va[j] - __uint_as_float(((uint)h) << 16));
                    ushort g = f2bf(vb[j]);
                    bh[c4 * 4 + j] = g;
                    bl[c4 * 4 + j] = f2bf(vb[j] - __uint_as_float(((uint)g) << 16));
                }
            }
            const int off = row * 72 + kq;
            *(uint4*)&As_hi[off]     = pack8(ah);
            *(uint4*)&As_hi[off + 8] = pack8(ah + 8);
            *(uint4*)&As_lo[off]     = pack8(al);
            *(uint4*)&As_lo[off + 8] = pack8(al + 8);
            *(uint4*)&Bs_hi[off]     = pack8(bh);
            *(uint4*)&Bs_hi[off + 8] = pack8(bh + 8);
            *(uint4*)&Bs_lo[off]     = pack8(bl);
            *(uint4*)&Bs_lo[off + 8] = pack8(bl + 8);
        }
        __syncthreads();
        if (kb + 64 < FIN) {   // prefetch next panel during compute
#pragma unroll
            for (int c = 0; c < 4; ++c) {
                pa[c] = *(const float4*)(xrow + kb + 64 + c * 4);
                pb[c] = *(const float4*)(wrow + kb + 64 + c * 4);
            }
        }
#pragma unroll
        for (int ch = 0; ch < 2; ++ch) {
            const int ko = ch * 32 + lq * 8;
            short8 ah[2], al[2], bh[2], bl[2];
#pragma unroll
            for (int si = 0; si < 2; ++si) {
                ah[si] = *(const short8*)&As_hi[(mbase + si * 16 + lm) * 72 + ko];
                al[si] = *(const short8*)&As_lo[(mbase + si * 16 + lm) * 72 + ko];
            }
#pragma unroll
            for (int ti = 0; ti < 2; ++ti) {
                bh[ti] = *(const short8*)&Bs_hi[(nbase + ti * 16 + lm) * 72 + ko];
                bl[ti] = *(const short8*)&Bs_lo[(nbase + ti * 16 + lm) * 72 + ko];
            }
#pragma unroll
            for (int si = 0; si < 2; ++si)
#pragma unroll
                for (int ti = 0; ti < 2; ++ti) {
                    acc[si][ti] = __builtin_amdgcn_mfma_f32_16x16x32_bf16(
                        ah[si], bh[ti], acc[si][ti], 0, 0, 0);
                    acc[si][ti] = __builtin_amdgcn_mfma_f32_16x16x32_bf16(
                        al[si], bh[ti], acc[si][ti], 0, 0, 0);
                    acc[si][ti] = __builtin_amdgcn_mfma_f32_16x16x32_bf16(
                        ah[si], bl[ti], acc[si][ti], 0, 0, 0);
                }
        }
    }

    // epilogue: bias, clamp, per-token l1norm over 64 outs, store.
    // C/D layout: col = lane&15 (n), row = (lane>>4)*4 + r (m) [m89-verified].
    const int half = wv & 1;
    const float b0 = eb[head * 64 + nbase + lm];
    const float b1 = eb[head * 64 + nbase + 16 + lm];
    float xe[2][2][4];
#pragma unroll
    for (int si = 0; si < 2; ++si) {
        float rs[4];
#pragma unroll
        for (int r = 0; r < 4; ++r) {
            float e0 = fmaxf(acc[si][0][r] + b0, 1e-6f);
            float e1 = fmaxf(acc[si][1][r] + b1, 1e-6f);
            xe[si][0][r] = e0; xe[si][1][r] = e1;
            rs[r] = e0 + e1;
        }
#pragma unroll
        for (int r = 0; r < 4; ++r) {
            rs[r] += __shfl_xor(rs[r], 1, 64);
            rs[r] += __shfl_xor(rs[r], 2, 64);
            rs[r] += __shfl_xor(rs[r], 4, 64);
            rs[r] += __shfl_xor(rs[r], 8, 64);
        }
        if (lm == 0) {
#pragma unroll
            for (int r = 0; r < 4; ++r)
                RS[half][mbase + si * 16 + lq * 4 + r] = rs[r];
        }
    }
    __syncthreads();
    const size_t obase = ((size_t)((tok0 >> 10) * 12 + head) * 1024 + (tok0 & 1023));
#pragma unroll
    for (int si = 0; si < 2; ++si)
#pragma unroll
        for (int r = 0; r < 4; ++r) {
            const int m = mbase + si * 16 + lq * 4 + r;
            const float inv = 1.f / fmaxf(RS[0][m] + RS[1][m], 1e-20f);
            float* op = inp + (obase + m) * 64;
            op[nbase + lm]      = xe[si][0][r] * inv;
            op[nbase + 16 + lm] = xe[si][1][r] * inv;
        }
}

// ---------------------------------------------------------------------------
// K3: NNMF updates, 1536 blocks, wave = 4 token-heads as 2 ILP pairs.
// Iteration 1 collapsed: rec1 is token-independent (precomputed r1inv),
// so it1 needs only the W^T matvec. Fuses it=0 alpha partial into mp0.
// ---------------------------------------------------------------------------
__global__ __launch_bounds__(256) void k_nnmf(const float* __restrict__ inp,
                                              const float* __restrict__ Wn,
                                              const float* __restrict__ WnT,
                                              const float* __restrict__ r1inv,
                                              float* __restrict__ hout,
                                              float* __restrict__ hriout,
                                              float* __restrict__ mp0) {
    const int tid = threadIdx.x;
    const int lane = tid & 63;
    float wcol[64], wrw[64];
#pragma unroll
    for (int f = 0; f < 64; ++f) wcol[f] = Wn[f * 64 + lane];   // W[f][lane]
#pragma unroll
    for (int d = 0; d < 64; ++d) wrw[d] = WnT[d * 64 + lane];   // W[lane][d]
    const float r1v = r1inv[lane];

    const int wid = blockIdx.x * 4 + (tid >> 6);
    float hsum = 0.f;
    for (int tt = 0; tt < 2; ++tt) {
        const int th0 = wid * 4 + tt * 2;
        const size_t base = (size_t)th0 * 64;
        float iv[2] = {inp[base + lane], inp[base + 64 + lane]};
        float hv[2], rec[2] = {0.f, 0.f};
        {   // ---- iteration 1 (rec = rec1, constant across tokens) ----
            float q[2] = {iv[0] * r1v, iv[1] * r1v};
            float ua[2] = {0.f, 0.f}, ub[2] = {0.f, 0.f};
#pragma unroll
            for (int d = 0; d < 64; d += 2) {
#pragma unroll
                for (int p = 0; p < 2; ++p) {
                    ua[p] = fmaf(bcast_lane(q[p], d    ), wrw[d    ], ua[p]);
                    ub[p] = fmaf(bcast_lane(q[p], d + 1), wrw[d + 1], ub[p]);
                }
            }
            float hn[2];
            hn[0] = fmaxf((ua[0] + ub[0]) * (1.f / 64.f), 1e-6f);
            hn[1] = fmaxf((ua[1] + ub[1]) * (1.f / 64.f), 1e-6f);
            float wn[2] = {hn[0], hn[1]};
            wsum64x2(wn[0], wn[1]);
            hv[0] = hn[0] / fmaxf(wn[0], 1e-20f);
            hv[1] = hn[1] / fmaxf(wn[1], 1e-20f);
        }
        for (int it = 0; it < 2; ++it) {   // ---- iterations 2,3 (full) ----
            float ta[2] = {0.f, 0.f}, tb[2] = {0.f, 0.f};
#pragma unroll
            for (int f = 0; f < 64; f += 2) {
#pragma unroll
                for (int p = 0; p < 2; ++p) {
                    ta[p] = fmaf(bcast_lane(hv[p], f    ), wcol[f    ], ta[p]);
                    tb[p] = fmaf(bcast_lane(hv[p], f + 1), wcol[f + 1], tb[p]);
                }
            }
            float t[2], w[2];
            t[0] = fmaxf(ta[0] + tb[0], 1e-6f);
            t[1] = fmaxf(ta[1] + tb[1], 1e-6f);
            w[0] = t[0]; w[1] = t[1];
            wsum64x2(w[0], w[1]);
            rec[0] = t[0] / fmaxf(w[0], 1e-20f);
            rec[1] = t[1] / fmaxf(w[1], 1e-20f);
            float q[2] = {iv[0] / rec[0], iv[1] / rec[1]};
            float ua[2] = {0.f, 0.f}, ub[2] = {0.f, 0.f};
#pragma unroll
            for (int d = 0; d < 64; d += 2) {
#pragma unroll
                for (int p = 0; p < 2; ++p) {
                    ua[p] = fmaf(bcast_lane(q[p], d    ), wrw[d    ], ua[p]);
                    ub[p] = fmaf(bcast_lane(q[p], d + 1), wrw[d + 1], ub[p]);
                }
            }
            float hn[2];
            hn[0] = fmaxf(hv[0] * (ua[0] + ub[0]), 1e-6f);
            hn[1] = fmaxf(hv[1] * (ua[1] + ub[1]), 1e-6f);
            float wn[2] = {hn[0], hn[1]};
            wsum64x2(wn[0], wn[1]);
            hv[0] = hn[0] / fmaxf(wn[0], 1e-20f);
            hv[1] = hn[1] / fmaxf(wn[1], 1e-20f);
        }
        float fs[2] = {hv[0], hv[1]};
        wsum64x2(fs[0], fs[1]);
        hv[0] = hv[0] / fmaxf(fs[0], 1e-20f);
        hv[1] = hv[1] / fmaxf(fs[1], 1e-20f);
        hout[base + lane] = hv[0];
        hout[base + 64 + lane] = hv[1];
        hriout[base + lane] = rec[0] * iv[0];
        hriout[base + 64 + lane] = rec[1] * iv[1];
        hsum += hv[0] + hv[1];
    }
    atomicAdd(&mp0[(size_t)(wid >> 4) * 64 + lane], hsum);
}

// ---------------------------------------------------------------------------
// K4: one alpha iteration per launch, 384 blocks = (bh) x (64-o chunk).
//   m = sum of 16 chunk partials; v = 1/(mW+eps); c[o] *= hri[o]·v; emit
//   partial m (it<3) or atomicAdd into M (it==3).
// ---------------------------------------------------------------------------
__global__ __launch_bounds__(256) void k_alpha_step(const float* __restrict__ hin,
                                                    const float* __restrict__ hri,
                                                    const float* __restrict__ Wn,
                                                    const float* __restrict__ mp_in,
                                                    float* __restrict__ mp_out,
                                                    float* __restrict__ c,
                                                    float* __restrict__ M,
                                                    int it) {
    __shared__ float mred[4][64];
    __shared__ float mv[64];
    __shared__ float vv[64];
    __shared__ float cl[64];
    const int tid = threadIdx.x;
    const int bh = blockIdx.x >> 4;
    const int chunk = blockIdx.x & 15;
    const size_t rowbase = (size_t)bh * 1024 + chunk * 64;

    {
        int f = tid & 63, p = tid >> 6;
        float s = 0.f;
#pragma unroll
        for (int pp = 0; pp < 4; ++pp)
            s += mp_in[((size_t)bh * 16 + p * 4 + pp) * 64 + f];
        mred[p][f] = s;
    }
    __syncthreads();
    if (tid < 64)
        mv[tid] = (mred[0][tid] + mred[1][tid]) + (mred[2][tid] + mred[3][tid]);
    __syncthreads();
    {
        int d = tid & 63, qq = tid >> 6;
        float r = 0.f;
#pragma unroll
        for (int ff = 0; ff < 16; ++ff)
            r = fmaf(mv[qq * 16 + ff], Wn[(size_t)(qq * 16 + ff) * 64 + d], r);
        mred[qq][d] = r;
    }
    __syncthreads();
    if (tid < 64)
        vv[tid] = 1.f / (((mred[0][tid] + mred[1][tid]) + (mred[2][tid] + mred[3][tid])) + 1e-20f);
    __syncthreads();
    {
        int o = tid >> 2, dq = tid & 3;
        const float* rp = hri + (rowbase + o) * 64 + dq * 16;
        float dot = 0.f;
#pragma unroll
        for (int t4 = 0; t4 < 16; t4 += 4) {
            float4 r4 = *(const float4*)(rp + t4);
            dot = fmaf(r4.x, vv[dq * 16 + t4 + 0], dot);
            dot = fmaf(r4.y, vv[dq * 16 + t4 + 1], dot);
            dot = fmaf(r4.z, vv[dq * 16 + t4 + 2], dot);
            dot = fmaf(r4.w, vv[dq * 16 + t4 + 3], dot);
        }
        dot += __shfl_xor(dot, 1, 64);
        dot += __shfl_xor(dot, 2, 64);
        float cn = dot;
        if (it >= 2) cn *= c[rowbase + o];
        if (dq == 0) { c[rowbase + o] = cn; cl[o] = cn; }
    }
    __syncthreads();
    {
        const int f4 = (tid & 15) * 4, ogr = tid >> 4;
        float4 a = make_float4(0.f, 0.f, 0.f, 0.f);
#pragma unroll
        for (int oi = 0; oi < 4; ++oi) {
            int o = ogr * 4 + oi;
            float4 h4 = *(const float4*)(hin + (rowbase + o) * 64 + f4);
            float cv = cl[o];
            a.x = fmaf(h4.x, cv, a.x); a.y = fmaf(h4.y, cv, a.y);
            a.z = fmaf(h4.z, cv, a.z); a.w = fmaf(h4.w, cv, a.w);
        }
        a.x += __shfl_xor(a.x, 16, 64); a.y += __shfl_xor(a.y, 16, 64);
        a.z += __shfl_xor(a.z, 16, 64); a.w += __shfl_xor(a.w, 16, 64);
        a.x += __shfl_xor(a.x, 32, 64); a.y += __shfl_xor(a.y, 32, 64);
        a.z += __shfl_xor(a.z, 32, 64); a.w += __shfl_xor(a.w, 32, 64);
        const int w = tid >> 6;
        if ((tid & 63) < 16) *(float4*)&mred[w][(tid & 15) * 4] = a;
    }
    __syncthreads();
    if (tid < 64) {
        float s = (mred[0][tid] + mred[1][tid]) + (mred[2][tid] + mred[3][tid]);
        if (it == 3) atomicAdd(&M[(size_t)bh * 64 + tid], s);
        else mp_out[((size_t)bh * 16 + chunk) * 64 + tid] = s;
    }
}

// ---------------------------------------------------------------------------
// K5: out-projection + broadcast, 384 blocks = (b) x (12 out-seg) x (16 rowgrp).
// ---------------------------------------------------------------------------
__global__ __launch_bounds__(256) void k_projbcast(const float* __restrict__ M,
                                                   const float* __restrict__ ow,
                                                   const float* __restrict__ ob,
                                                   float* __restrict__ out) {
    __shared__ float Ml[768];
    __shared__ float ps[4][64];
    __shared__ float yseg[64];
    const int tid = threadIdx.x;
    const int b = blockIdx.x / 192;
    const int rem = blockIdx.x - b * 192;
    const int jt = rem >> 4, rg = rem & 15;
    for (int i = tid; i < 768; i += 256) Ml[i] = M[b * 768 + i];
    __syncthreads();
    const int jj = tid & 63, part = tid >> 6;
    const int j = jt * 64 + jj;
    const float* row = ow + (size_t)j * 768 + part * 192;
    float acc = 0.f;
    for (int t = 0; t < 192; t += 4) {
        float4 w4 = *(const float4*)(row + t);
        acc = fmaf(w4.x, Ml[part * 192 + t + 0], acc);
        acc = fmaf(w4.y, Ml[part * 192 + t + 1], acc);
        acc = fmaf(w4.z, Ml[part * 192 + t + 2], acc);
        acc = fmaf(w4.w, Ml[part * 192 + t + 3], acc);
    }
    ps[part][jj] = acc;
    __syncthreads();
    if (tid < 64)
        yseg[tid] = ps[0][tid] + ps[1][tid] + ps[2][tid] + ps[3][tid] + ob[jt * 64 + tid];
    __syncthreads();
    const int r0 = tid >> 2, c4 = (tid & 3) * 16;
    float4 v4[4];
#pragma unroll
    for (int q = 0; q < 4; ++q) v4[q] = *(const float4*)&yseg[c4 + q * 4];
    float* dst = out + ((size_t)(b * 1024 + rg * 64 + r0)) * 768 + jt * 64 + c4;
#pragma unroll
    for (int q = 0; q < 4; ++q) *(float4*)(dst + q * 4) = v4[q];
}

extern "C" void kernel_launch(void* const* d_in, const int* in_sizes, int n_in,
                              void* d_out, int out_size, void* d_ws, size_t ws_size,
                              hipStream_t stream) {
    const float* xs = (const float*)d_in[0];  // [2,1024,768]
    const float* ew = (const float*)d_in[1];  // [768,768]
    const float* eb = (const float*)d_in[2];  // [768]
    const float* nw = (const float*)d_in[3];  // [64,64]
    const float* ow = (const float*)d_in[4];  // [768,768]
    const float* ob = (const float*)d_in[5];  // [768]
    float* out = (float*)d_out;               // [2,1024,768]

    float* ws    = (float*)d_ws;
    float* inp   = ws;                 // 1572864
    float* h     = ws + 1572864;       // 1572864
    float* hri   = ws + 3145728;       // 1572864
    float* Wn    = ws + 4718592;       // 4096
    float* WnT   = ws + 4722688;       // 4096
    float* r1inv = ws + 4726784;       // 64 (padded to 256)
    float* mp0   = ws + 4727040;       // 24576 (atomic target, zeroed by wprep)
    float* M     = ws + 4751616;       // 1536  (atomic target, zeroed by wprep)
    float* mp1   = ws + 4753152;       // 24576
    float* mp2   = ws + 4777728;       // 24576
    float* c     = ws + 4802304;       // 24576

    k_wprep<<<27, 256, 0, stream>>>(nw, Wn, WnT, r1inv, mp0);
    k_embed<<<dim3(32, 12), 256, 0, stream>>>(xs, ew, eb, inp);
    k_nnmf<<<1536, 256, 0, stream>>>(inp, Wn, WnT, r1inv, h, hri, mp0);
    k_alpha_step<<<384, 256, 0, stream>>>(h, hri, Wn, mp0, mp1, c, M, 1);
    k_alpha_step<<<384, 256, 0, stream>>>(h, hri, Wn, mp1, mp2, c, M, 2);
    k_alpha_step<<<384, 256, 0, stream>>>(h, hri, Wn, mp2, mp1, c, M, 3);
    k_projbcast<<<384, 256, 0, stream>>>(M, ow, ob, out);
}

// Round 8
// 143.511 us; speedup vs baseline: 2.1429x; 1.0976x over previous
//
#include <hip/hip_runtime.h>

// Problem constants
#define B_  2
#define S_  1024
#define FIN 768
#define E_  768
#define H_  12
#define DH  64   // = FH = 64

typedef unsigned int uint;
typedef unsigned short ushort;
typedef __attribute__((ext_vector_type(8))) short short8;    // 8 bf16 (4 VGPRs)
typedef __attribute__((ext_vector_type(4))) float floatx4;   // MFMA acc

__device__ __forceinline__ ushort f2bf(float f) {   // RNE float->bf16 bits
    uint u = __float_as_uint(f);
    return (ushort)((u + 0x7fffu + ((u >> 16) & 1u)) >> 16);
}

__device__ __forceinline__ uint4 pack8(const ushort* p) {
    uint4 r;
    r.x = (uint)p[0] | ((uint)p[1] << 16);
    r.y = (uint)p[2] | ((uint)p[3] << 16);
    r.z = (uint)p[4] | ((uint)p[5] << 16);
    r.w = (uint)p[6] | ((uint)p[7] << 16);
    return r;
}

__device__ __forceinline__ void split8v(float4 a, float4 b, short8& hi, short8& lo) {
    float v[8] = {a.x, a.y, a.z, a.w, b.x, b.y, b.z, b.w};
    ushort h[8], l[8];
#pragma unroll
    for (int j = 0; j < 8; ++j) {
        h[j] = f2bf(v[j]);
        l[j] = f2bf(v[j] - __uint_as_float(((uint)h[j]) << 16));
    }
    uint4 H = pack8(h), L = pack8(l);
    hi = *(short8*)&H;
    lo = *(short8*)&L;
}

// ---------------------------------------------------------------------------
// K1: block 0: Wn/WnT (row-normalized nnmf_w) + r1inv (iteration-1 collapsed
// reconstruction). Blocks 1..26: zero mp0 (24576) + M (1536).
// ---------------------------------------------------------------------------
__global__ __launch_bounds__(256) void k_wprep(const float* __restrict__ nw,
                                               float* __restrict__ Wn,
                                               float* __restrict__ WnT,
                                               float* __restrict__ r1inv,
                                               float* __restrict__ zbase) {
    const int tid = threadIdx.x;
    if (blockIdx.x == 0) {
        __shared__ float Wl[64 * 65];
        const int f = tid >> 2, q = tid & 3;
        float v[16];
        float s = 0.f;
#pragma unroll
        for (int i = 0; i < 16; ++i) { v[i] = nw[f * 64 + q * 16 + i]; s += v[i]; }
        s += __shfl_xor(s, 1, 64);
        s += __shfl_xor(s, 2, 64);
        const float inv = 1.f / fmaxf(s, 1e-20f);
#pragma unroll
        for (int i = 0; i < 16; ++i) {
            float w = v[i] * inv;
            Wn[f * 64 + q * 16 + i] = w;
            WnT[(q * 16 + i) * 64 + f] = w;
            Wl[f * 65 + q * 16 + i] = w;
        }
        __syncthreads();
        if (tid < 64) {
            float cs = 0.f;
            for (int ff = 0; ff < 64; ++ff) cs += Wl[ff * 65 + tid];
            float t = fmaxf(cs * (1.f / 64.f), 1e-6f);
            float S = t;
#pragma unroll
            for (int m = 1; m < 64; m <<= 1) S += __shfl_xor(S, m, 64);
            S = fmaxf(S, 1e-20f);
            r1inv[tid] = S / t;   // 1/rec1
        }
    } else {
        const int i = (blockIdx.x - 1) * 1024 + tid * 4;
        if (i < 26112) {
            float4 z = make_float4(0.f, 0.f, 0.f, 0.f);
            *(float4*)(zbase + i) = z;
        }
    }
}

// ---------------------------------------------------------------------------
// K2 (MFMA, passed R7): xe = clip(x @ embed_w^T + b, 1e-6); inp = l1norm/head.
// ---------------------------------------------------------------------------
__global__ __launch_bounds__(256) void k_embed(const float* __restrict__ xs,
                                               const float* __restrict__ ew,
                                               const float* __restrict__ eb,
                                               float* __restrict__ inp) {
    __shared__ ushort As_hi[64 * 72], As_lo[64 * 72];
    __shared__ ushort Bs_hi[64 * 72], Bs_lo[64 * 72];
    __shared__ float RS[2][64];
    const int tid = threadIdx.x;
    const int head = blockIdx.y;
    const int tok0 = blockIdx.x * 64;
    const int wv = tid >> 6, lane = tid & 63;
    const int mbase = (wv >> 1) * 32, nbase = (wv & 1) * 32;
    const int lm = lane & 15, lq = lane >> 4;

    floatx4 acc[2][2];
#pragma unroll
    for (int si = 0; si < 2; ++si)
#pragma unroll
        for (int ti = 0; ti < 2; ++ti) acc[si][ti] = (floatx4)0.f;

    const int row = tid >> 2;
    const int kq = (tid & 3) * 16;
    const float* xrow = xs + (size_t)(tok0 + row) * FIN + kq;
    const float* wrow = ew + (size_t)(head * 64 + row) * FIN + kq;

    float4 pa[4], pb[4];
#pragma unroll
    for (int c = 0; c < 4; ++c) {
        pa[c] = *(const float4*)(xrow + c * 4);
        pb[c] = *(const float4*)(wrow + c * 4);
    }

    for (int kb = 0; kb < FIN; kb += 64) {
        __syncthreads();
        {
            ushort ah[16], al[16], bh[16], bl[16];
#pragma unroll
            for (int c4 = 0; c4 < 4; ++c4) {
                float va[4] = {pa[c4].x, pa[c4].y, pa[c4].z, pa[c4].w};
                float vb[4] = {pb[c4].x, pb[c4].y, pb[c4].z, pb[c4].w};
#pragma unroll
                for (int j = 0; j < 4; ++j) {
                    ushort h = f2bf(va[j]);
                    ah[c4 * 4 + j] = h;
                    al[c4 * 4 + j] = f2bf(va[j] - __uint_as_float(((uint)h) << 16));
                    ushort g = f2bf(vb[j]);
                    bh[c4 * 4 + j] = g;
                    bl[c4 * 4 + j] = f2bf(vb[j] - __uint_as_float(((uint)g) << 16));
                }
            }
            const int off = row * 72 + kq;
            *(uint4*)&As_hi[off]     = pack8(ah);
            *(uint4*)&As_hi[off + 8] = pack8(ah + 8);
            *(uint4*)&As_lo[off]     = pack8(al);
            *(uint4*)&As_lo[off + 8] = pack8(al + 8);
            *(uint4*)&Bs_hi[off]     = pack8(bh);
            *(uint4*)&Bs_hi[off + 8] = pack8(bh + 8);
            *(uint4*)&Bs_lo[off]     = pack8(bl);
            *(uint4*)&Bs_lo[off + 8] = pack8(bl + 8);
        }
        __syncthreads();
        if (kb + 64 < FIN) {
#pragma unroll
            for (int c = 0; c < 4; ++c) {
                pa[c] = *(const float4*)(xrow + kb + 64 + c * 4);
                pb[c] = *(const float4*)(wrow + kb + 64 + c * 4);
            }
        }
#pragma unroll
        for (int ch = 0; ch < 2; ++ch) {
            const int ko = ch * 32 + lq * 8;
            short8 ah[2], al[2], bh[2], bl[2];
#pragma unroll
            for (int si = 0; si < 2; ++si) {
                ah[si] = *(const short8*)&As_hi[(mbase + si * 16 + lm) * 72 + ko];
                al[si] = *(const short8*)&As_lo[(mbase + si * 16 + lm) * 72 + ko];
            }
#pragma unroll
            for (int ti = 0; ti < 2; ++ti) {
                bh[ti] = *(const short8*)&Bs_hi[(nbase + ti * 16 + lm) * 72 + ko];
                bl[ti] = *(const short8*)&Bs_lo[(nbase + ti * 16 + lm) * 72 + ko];
            }
#pragma unroll
            for (int si = 0; si < 2; ++si)
#pragma unroll
                for (int ti = 0; ti < 2; ++ti) {
                    acc[si][ti] = __builtin_amdgcn_mfma_f32_16x16x32_bf16(
                        ah[si], bh[ti], acc[si][ti], 0, 0, 0);
                    acc[si][ti] = __builtin_amdgcn_mfma_f32_16x16x32_bf16(
                        al[si], bh[ti], acc[si][ti], 0, 0, 0);
                    acc[si][ti] = __builtin_amdgcn_mfma_f32_16x16x32_bf16(
                        ah[si], bl[ti], acc[si][ti], 0, 0, 0);
                }
        }
    }

    const int half = wv & 1;
    const float b0 = eb[head * 64 + nbase + lm];
    const float b1 = eb[head * 64 + nbase + 16 + lm];
    float xe[2][2][4];
#pragma unroll
    for (int si = 0; si < 2; ++si) {
        float rs[4];
#pragma unroll
        for (int r = 0; r < 4; ++r) {
            float e0 = fmaxf(acc[si][0][r] + b0, 1e-6f);
            float e1 = fmaxf(acc[si][1][r] + b1, 1e-6f);
            xe[si][0][r] = e0; xe[si][1][r] = e1;
            rs[r] = e0 + e1;
        }
#pragma unroll
        for (int r = 0; r < 4; ++r) {
            rs[r] += __shfl_xor(rs[r], 1, 64);
            rs[r] += __shfl_xor(rs[r], 2, 64);
            rs[r] += __shfl_xor(rs[r], 4, 64);
            rs[r] += __shfl_xor(rs[r], 8, 64);
        }
        if (lm == 0) {
#pragma unroll
            for (int r = 0; r < 4; ++r)
                RS[half][mbase + si * 16 + lq * 4 + r] = rs[r];
        }
    }
    __syncthreads();
    const size_t obase = ((size_t)((tok0 >> 10) * 12 + head) * 1024 + (tok0 & 1023));
#pragma unroll
    for (int si = 0; si < 2; ++si)
#pragma unroll
        for (int r = 0; r < 4; ++r) {
            const int m = mbase + si * 16 + lq * 4 + r;
            const float inv = 1.f / fmaxf(RS[0][m] + RS[1][m], 1e-20f);
            float* op = inp + (obase + m) * 64;
            op[nbase + lm]      = xe[si][0][r] * inv;
            op[nbase + 16 + lm] = xe[si][1][r] * inv;
        }
}

// ---------------------------------------------------------------------------
// K3 v3 (MFMA): NNMF updates, 16 tokens per wave, 384 blocks x 4 waves.
// Matvecs as 16x64 @ 64x64 GEMMs via split-bf16 mfma_f32_16x16x32_bf16.
// State in C-layout fp32 regs (col=lane&15 -> d/f within n-tile,
// row=(lane>>4)*4+reg -> token). A-operand transform via wave-private LDS.
// Iteration 1 collapsed (r1inv). Fuses it=0 alpha partial into mp0.
// ---------------------------------------------------------------------------
__device__ __forceinline__ void mfma_matvec(const float srcC[4][4], float* T,
                                            int lm, int lq,
                                            const short8 Bh[4][2],
                                            const short8 Bl[4][2],
                                            floatx4 out[4]) {
    // C-layout -> LDS [token][f] (2-way conflicts only)
#pragma unroll
    for (int nt = 0; nt < 4; ++nt)
#pragma unroll
        for (int r = 0; r < 4; ++r)
            T[(lq * 4 + r) * 68 + nt * 16 + lm] = srcC[nt][r];
    __syncthreads();
    float4 a00 = *(const float4*)&T[lm * 68 + lq * 8];
    float4 a01 = *(const float4*)&T[lm * 68 + lq * 8 + 4];
    float4 a10 = *(const float4*)&T[lm * 68 + 32 + lq * 8];
    float4 a11 = *(const float4*)&T[lm * 68 + 32 + lq * 8 + 4];
    short8 A0h, A0l, A1h, A1l;
    split8v(a00, a01, A0h, A0l);
    split8v(a10, a11, A1h, A1l);
#pragma unroll
    for (int nt = 0; nt < 4; ++nt) {
        floatx4 acc = (floatx4)0.f;
        acc = __builtin_amdgcn_mfma_f32_16x16x32_bf16(A0h, Bh[nt][0], acc, 0, 0, 0);
        acc = __builtin_amdgcn_mfma_f32_16x16x32_bf16(A0l, Bh[nt][0], acc, 0, 0, 0);
        acc = __builtin_amdgcn_mfma_f32_16x16x32_bf16(A0h, Bl[nt][0], acc, 0, 0, 0);
        acc = __builtin_amdgcn_mfma_f32_16x16x32_bf16(A1h, Bh[nt][1], acc, 0, 0, 0);
        acc = __builtin_amdgcn_mfma_f32_16x16x32_bf16(A1l, Bh[nt][1], acc, 0, 0, 0);
        acc = __builtin_amdgcn_mfma_f32_16x16x32_bf16(A1h, Bl[nt][1], acc, 0, 0, 0);
        out[nt] = acc;
    }
}

__global__ __launch_bounds__(256) void k_nnmf(const float* __restrict__ inp,
                                              const float* __restrict__ Wn,
                                              const float* __restrict__ WnT,
                                              const float* __restrict__ r1inv,
                                              float* __restrict__ hout,
                                              float* __restrict__ hriout,
                                              float* __restrict__ mp0) {
    __shared__ float Tb[4][16 * 68];
    const int tid = threadIdx.x, wv = tid >> 6, lane = tid & 63;
    const int lm = lane & 15, lq = lane >> 4;
    float* T = Tb[wv];
    const int rowbase = blockIdx.x * 64 + wv * 16;

    // B-fragments: matvec1 (t = h@W): B[n=d][k=f] from WnT (contiguous);
    //              matvec2 (u = q@W^T): B[n=f][k=d] from Wn (contiguous).
    short8 Bt_h[4][2], Bt_l[4][2], Bw_h[4][2], Bw_l[4][2];
#pragma unroll
    for (int nt = 0; nt < 4; ++nt)
#pragma unroll
        for (int kc = 0; kc < 2; ++kc) {
            const int idx = (nt * 16 + lm) * 64 + kc * 32 + lq * 8;
            split8v(*(const float4*)(WnT + idx), *(const float4*)(WnT + idx + 4),
                    Bt_h[nt][kc], Bt_l[nt][kc]);
            split8v(*(const float4*)(Wn + idx), *(const float4*)(Wn + idx + 4),
                    Bw_h[nt][kc], Bw_l[nt][kc]);
        }

    // inp in C-layout
    float inpC[4][4];
#pragma unroll
    for (int nt = 0; nt < 4; ++nt)
#pragma unroll
        for (int r = 0; r < 4; ++r)
            inpC[nt][r] = inp[(size_t)(rowbase + lq * 4 + r) * 64 + nt * 16 + lm];
    float r1c[4];
#pragma unroll
    for (int nt = 0; nt < 4; ++nt) r1c[nt] = r1inv[nt * 16 + lm];

    float hC[4][4], recC[4][4];
    // ---- iteration 1 (rec1 token-independent) ----
    {
        float qC[4][4];
#pragma unroll
        for (int nt = 0; nt < 4; ++nt)
#pragma unroll
            for (int r = 0; r < 4; ++r) qC[nt][r] = inpC[nt][r] * r1c[nt];
        floatx4 u[4];
        mfma_matvec(qC, T, lm, lq, Bw_h, Bw_l, u);
#pragma unroll
        for (int nt = 0; nt < 4; ++nt)
#pragma unroll
            for (int r = 0; r < 4; ++r)
                hC[nt][r] = fmaxf(u[nt][r] * (1.f / 64.f), 1e-6f);
#pragma unroll
        for (int r = 0; r < 4; ++r) {
            float s = (hC[0][r] + hC[1][r]) + (hC[2][r] + hC[3][r]);
            s += __shfl_xor(s, 1, 64); s += __shfl_xor(s, 2, 64);
            s += __shfl_xor(s, 4, 64); s += __shfl_xor(s, 8, 64);
            const float inv = __builtin_amdgcn_rcpf(fmaxf(s, 1e-20f));
#pragma unroll
            for (int nt = 0; nt < 4; ++nt) hC[nt][r] *= inv;
        }
    }
    // ---- iterations 2,3 (full) ----
#pragma unroll 1
    for (int it = 0; it < 2; ++it) {
        floatx4 t[4];
        mfma_matvec(hC, T, lm, lq, Bt_h, Bt_l, t);
        float tC[4][4], qC[4][4];
#pragma unroll
        for (int nt = 0; nt < 4; ++nt)
#pragma unroll
            for (int r = 0; r < 4; ++r) tC[nt][r] = fmaxf(t[nt][r], 1e-6f);
#pragma unroll
        for (int r = 0; r < 4; ++r) {
            float s = (tC[0][r] + tC[1][r]) + (tC[2][r] + tC[3][r]);
            s += __shfl_xor(s, 1, 64); s += __shfl_xor(s, 2, 64);
            s += __shfl_xor(s, 4, 64); s += __shfl_xor(s, 8, 64);
            s = fmaxf(s, 1e-20f);
            const float invS = __builtin_amdgcn_rcpf(s);
#pragma unroll
            for (int nt = 0; nt < 4; ++nt) {
                recC[nt][r] = tC[nt][r] * invS;                         // rec = t/S
                qC[nt][r] = inpC[nt][r] * s * __builtin_amdgcn_rcpf(tC[nt][r]); // inp/rec
            }
        }
        floatx4 u[4];
        mfma_matvec(qC, T, lm, lq, Bw_h, Bw_l, u);
#pragma unroll
        for (int nt = 0; nt < 4; ++nt)
#pragma unroll
            for (int r = 0; r < 4; ++r)
                hC[nt][r] = fmaxf(hC[nt][r] * u[nt][r], 1e-6f);
#pragma unroll
        for (int r = 0; r < 4; ++r) {
            float s = (hC[0][r] + hC[1][r]) + (hC[2][r] + hC[3][r]);
            s += __shfl_xor(s, 1, 64); s += __shfl_xor(s, 2, 64);
            s += __shfl_xor(s, 4, 64); s += __shfl_xor(s, 8, 64);
            const float inv = __builtin_amdgcn_rcpf(fmaxf(s, 1e-20f));
#pragma unroll
            for (int nt = 0; nt < 4; ++nt) hC[nt][r] *= inv;
        }
    }
    // final l1norm of h (reference's normalize_h)
#pragma unroll
    for (int r = 0; r < 4; ++r) {
        float s = (hC[0][r] + hC[1][r]) + (hC[2][r] + hC[3][r]);
        s += __shfl_xor(s, 1, 64); s += __shfl_xor(s, 2, 64);
        s += __shfl_xor(s, 4, 64); s += __shfl_xor(s, 8, 64);
        const float inv = __builtin_amdgcn_rcpf(fmaxf(s, 1e-20f));
#pragma unroll
        for (int nt = 0; nt < 4; ++nt) hC[nt][r] *= inv;
    }
    // stores
#pragma unroll
    for (int nt = 0; nt < 4; ++nt)
#pragma unroll
        for (int r = 0; r < 4; ++r) {
            const size_t o = (size_t)(rowbase + lq * 4 + r) * 64 + nt * 16 + lm;
            hout[o] = hC[nt][r];
            hriout[o] = recC[nt][r] * inpC[nt][r];
        }
    // it=0 alpha partial: sum h over this wave's 16 tokens per f
    float hs[4];
#pragma unroll
    for (int nt = 0; nt < 4; ++nt) {
        float s = (hC[nt][0] + hC[nt][1]) + (hC[nt][2] + hC[nt][3]);
        s += __shfl_xor(s, 16, 64);
        s += __shfl_xor(s, 32, 64);
        hs[nt] = s;
    }
    float mvv = lq == 0 ? hs[0] : lq == 1 ? hs[1] : lq == 2 ? hs[2] : hs[3];
    atomicAdd(&mp0[(size_t)blockIdx.x * 64 + lq * 16 + lm], mvv);
}

// ---------------------------------------------------------------------------
// K4: one alpha iteration per launch, 384 blocks = (bh) x (64-o chunk).
// ---------------------------------------------------------------------------
__global__ __launch_bounds__(256) void k_alpha_step(const float* __restrict__ hin,
                                                    const float* __restrict__ hri,
                                                    const float* __restrict__ Wn,
                                                    const float* __restrict__ mp_in,
                                                    float* __restrict__ mp_out,
                                                    float* __restrict__ c,
                                                    float* __restrict__ M,
                                                    int it) {
    __shared__ float mred[4][64];
    __shared__ float mv[64];
    __shared__ float vv[64];
    __shared__ float cl[64];
    const int tid = threadIdx.x;
    const int bh = blockIdx.x >> 4;
    const int chunk = blockIdx.x & 15;
    const size_t rowbase = (size_t)bh * 1024 + chunk * 64;

    {
        int f = tid & 63, p = tid >> 6;
        float s = 0.f;
#pragma unroll
        for (int pp = 0; pp < 4; ++pp)
            s += mp_in[((size_t)bh * 16 + p * 4 + pp) * 64 + f];
        mred[p][f] = s;
    }
    __syncthreads();
    if (tid < 64)
        mv[tid] = (mred[0][tid] + mred[1][tid]) + (mred[2][tid] + mred[3][tid]);
    __syncthreads();
    {
        int d = tid & 63, qq = tid >> 6;
        float r = 0.f;
#pragma unroll
        for (int ff = 0; ff < 16; ++ff)
            r = fmaf(mv[qq * 16 + ff], Wn[(size_t)(qq * 16 + ff) * 64 + d], r);
        mred[qq][d] = r;
    }
    __syncthreads();
    if (tid < 64)
        vv[tid] = 1.f / (((mred[0][tid] + mred[1][tid]) + (mred[2][tid] + mred[3][tid])) + 1e-20f);
    __syncthreads();
    {
        int o = tid >> 2, dq = tid & 3;
        const float* rp = hri + (rowbase + o) * 64 + dq * 16;
        float dot = 0.f;
#pragma unroll
        for (int t4 = 0; t4 < 16; t4 += 4) {
            float4 r4 = *(const float4*)(rp + t4);
            dot = fmaf(r4.x, vv[dq * 16 + t4 + 0], dot);
            dot = fmaf(r4.y, vv[dq * 16 + t4 + 1], dot);
            dot = fmaf(r4.z, vv[dq * 16 + t4 + 2], dot);
            dot = fmaf(r4.w, vv[dq * 16 + t4 + 3], dot);
        }
        dot += __shfl_xor(dot, 1, 64);
        dot += __shfl_xor(dot, 2, 64);
        float cn = dot;
        if (it >= 2) cn *= c[rowbase + o];
        if (dq == 0) { c[rowbase + o] = cn; cl[o] = cn; }
    }
    __syncthreads();
    {
        const int f4 = (tid & 15) * 4, ogr = tid >> 4;
        float4 a = make_float4(0.f, 0.f, 0.f, 0.f);
#pragma unroll
        for (int oi = 0; oi < 4; ++oi) {
            int o = ogr * 4 + oi;
            float4 h4 = *(const float4*)(hin + (rowbase + o) * 64 + f4);
            float cv = cl[o];
            a.x = fmaf(h4.x, cv, a.x); a.y = fmaf(h4.y, cv, a.y);
            a.z = fmaf(h4.z, cv, a.z); a.w = fmaf(h4.w, cv, a.w);
        }
        a.x += __shfl_xor(a.x, 16, 64); a.y += __shfl_xor(a.y, 16, 64);
        a.z += __shfl_xor(a.z, 16, 64); a.w += __shfl_xor(a.w, 16, 64);
        a.x += __shfl_xor(a.x, 32, 64); a.y += __shfl_xor(a.y, 32, 64);
        a.z += __shfl_xor(a.z, 32, 64); a.w += __shfl_xor(a.w, 32, 64);
        const int w = tid >> 6;
        if ((tid & 63) < 16) *(float4*)&mred[w][(tid & 15) * 4] = a;
    }
    __syncthreads();
    if (tid < 64) {
        float s = (mred[0][tid] + mred[1][tid]) + (mred[2][tid] + mred[3][tid]);
        if (it == 3) atomicAdd(&M[(size_t)bh * 64 + tid], s);
        else mp_out[((size_t)bh * 16 + chunk) * 64 + tid] = s;
    }
}

// ---------------------------------------------------------------------------
// K5: out-projection + broadcast, 384 blocks = (b) x (12 out-seg) x (16 rowgrp).
// ---------------------------------------------------------------------------
__global__ __launch_bounds__(256) void k_projbcast(const float* __restrict__ M,
                                                   const float* __restrict__ ow,
                                                   const float* __restrict__ ob,
                                                   float* __restrict__ out) {
    __shared__ float Ml[768];
    __shared__ float ps[4][64];
    __shared__ float yseg[64];
    const int tid = threadIdx.x;
    const int b = blockIdx.x / 192;
    const int rem = blockIdx.x - b * 192;
    const int jt = rem >> 4, rg = rem & 15;
    for (int i = tid; i < 768; i += 256) Ml[i] = M[b * 768 + i];
    __syncthreads();
    const int jj = tid & 63, part = tid >> 6;
    const int j = jt * 64 + jj;
    const float* row = ow + (size_t)j * 768 + part * 192;
    float acc = 0.f;
    for (int t = 0; t < 192; t += 4) {
        float4 w4 = *(const float4*)(row + t);
        acc = fmaf(w4.x, Ml[part * 192 + t + 0], acc);
        acc = fmaf(w4.y, Ml[part * 192 + t + 1], acc);
        acc = fmaf(w4.z, Ml[part * 192 + t + 2], acc);
        acc = fmaf(w4.w, Ml[part * 192 + t + 3], acc);
    }
    ps[part][jj] = acc;
    __syncthreads();
    if (tid < 64)
        yseg[tid] = ps[0][tid] + ps[1][tid] + ps[2][tid] + ps[3][tid] + ob[jt * 64 + tid];
    __syncthreads();
    const int r0 = tid >> 2, c4 = (tid & 3) * 16;
    float4 v4[4];
#pragma unroll
    for (int q = 0; q < 4; ++q) v4[q] = *(const float4*)&yseg[c4 + q * 4];
    float* dst = out + ((size_t)(b * 1024 + rg * 64 + r0)) * 768 + jt * 64 + c4;
#pragma unroll
    for (int q = 0; q < 4; ++q) *(float4*)(dst + q * 4) = v4[q];
}

extern "C" void kernel_launch(void* const* d_in, const int* in_sizes, int n_in,
                              void* d_out, int out_size, void* d_ws, size_t ws_size,
                              hipStream_t stream) {
    const float* xs = (const float*)d_in[0];  // [2,1024,768]
    const float* ew = (const float*)d_in[1];  // [768,768]
    const float* eb = (const float*)d_in[2];  // [768]
    const float* nw = (const float*)d_in[3];  // [64,64]
    const float* ow = (const float*)d_in[4];  // [768,768]
    const float* ob = (const float*)d_in[5];  // [768]
    float* out = (float*)d_out;               // [2,1024,768]

    float* ws    = (float*)d_ws;
    float* inp   = ws;                 // 1572864
    float* h     = ws + 1572864;       // 1572864
    float* hri   = ws + 3145728;       // 1572864
    float* Wn    = ws + 4718592;       // 4096
    float* WnT   = ws + 4722688;       // 4096
    float* r1inv = ws + 4726784;       // 64 (padded to 256)
    float* mp0   = ws + 4727040;       // 24576 (atomic target, zeroed by wprep)
    float* M     = ws + 4751616;       // 1536  (atomic target, zeroed by wprep)
    float* mp1   = ws + 4753152;       // 24576
    float* mp2   = ws + 4777728;       // 24576
    float* c     = ws + 4802304;       // 24576

    k_wprep<<<27, 256, 0, stream>>>(nw, Wn, WnT, r1inv, mp0);
    k_embed<<<dim3(32, 12), 256, 0, stream>>>(xs, ew, eb, inp);
    k_nnmf<<<384, 256, 0, stream>>>(inp, Wn, WnT, r1inv, h, hri, mp0);
    k_alpha_step<<<384, 256, 0, stream>>>(h, hri, Wn, mp0, mp1, c, M, 1);
    k_alpha_step<<<384, 256, 0, stream>>>(h, hri, Wn, mp1, mp2, c, M, 2);
    k_alpha_step<<<384, 256, 0, stream>>>(h, hri, Wn, mp2, mp1, c, M, 3);
    k_projbcast<<<384, 256, 0, stream>>>(M, ow, ob, out);
}